// Round 1
// baseline (2145.956 us; speedup 1.0000x reference)
//
#include <hip/hip_runtime.h>
#include <hip/hip_bf16.h>

// Problem constants
#define B_   64
#define N_   128
#define E_   4096
#define P_   2048
#define DIN_ 512
#define DG_  256
#define EF_  256
#define HID_ 512
#define NH_  1536            // 3 heads * 512 hidden
#define MROWS_ (B_*P_)       // 131072 pair rows

typedef __attribute__((ext_vector_type(8))) short bf16x8;           // 8 bf16 (4 VGPRs)
typedef __attribute__((ext_vector_type(4))) float f32x4;            // MFMA C/D frag
typedef __attribute__((ext_vector_type(4))) unsigned short us4;

__device__ __forceinline__ unsigned short f2bf(float v) {
    union { float f; unsigned u; } x; x.f = v;
    unsigned r = x.u + 0x7FFFu + ((x.u >> 16) & 1u);   // RNE, finite inputs
    return (unsigned short)(r >> 16);
}
__device__ __forceinline__ float bf2f(unsigned short b) {
    union { unsigned u; float f; } x; x.u = ((unsigned)b) << 16;
    return x.f;
}
__device__ __forceinline__ f32x4 mfma16(bf16x8 a, bf16x8 b, f32x4 c) {
    return __builtin_amdgcn_mfma_f32_16x16x32_bf16(a, b, c, 0, 0, 0);
}

// ---------------- K1: dense adjacency init (I for self-loop) ----------------
__global__ __launch_bounds__(256) void k_init_adj(float* __restrict__ adjf) {
    int i = blockIdx.x * 256 + threadIdx.x;
    if (i >= B_*N_*N_) return;
    int r = (i >> 7) & 127, c = i & 127;
    adjf[i] = (r == c) ? 1.0f : 0.0f;
}

// ---------------- K2: scatter edge counts: adj[b][dst][src] += 1 ------------
__global__ __launch_bounds__(256) void k_scatter(const int* __restrict__ ei,
                                                 float* __restrict__ adjf) {
    int i = blockIdx.x * 256 + threadIdx.x;
    if (i >= B_*E_) return;
    int b = i >> 12, e = i & (E_ - 1);
    int src = ei[b*2*E_ + e];
    int dst = ei[b*2*E_ + E_ + e];
    atomicAdd(&adjf[(b*N_ + dst)*N_ + src], 1.0f);
}

// ---------------- K3: conversions / transposes / split-bf16 -----------------
__global__ __launch_bounds__(256) void k_prep(
    const float* __restrict__ adjf, const float* __restrict__ X,
    const float* __restrict__ Wg1, const float* __restrict__ Wg2,
    const float* __restrict__ W1lr, const float* __restrict__ W1cr, const float* __restrict__ W1mr,
    const float* __restrict__ W2lr, const float* __restrict__ W2cr, const float* __restrict__ W2mr,
    const float* __restrict__ b1lr, const float* __restrict__ b1cr, const float* __restrict__ b1mr,
    const float* __restrict__ b2lr, const float* __restrict__ b2cr, const float* __restrict__ b2mr,
    unsigned short* __restrict__ adjb,
    unsigned short* __restrict__ Xh, unsigned short* __restrict__ Xl,
    unsigned short* __restrict__ W1th, unsigned short* __restrict__ W1tl,
    unsigned short* __restrict__ W2th, unsigned short* __restrict__ W2tl,
    unsigned short* __restrict__ Wb, unsigned short* __restrict__ W2b,
    float* __restrict__ b1cat, float* __restrict__ b2pad)
{
    int i = blockIdx.x * 256 + threadIdx.x;
    if (i < B_*N_*N_) { adjb[i] = f2bf(adjf[i]); return; }   // exact (small ints)
    i -= B_*N_*N_;
    if (i < B_*N_*DIN_) {                                     // X split
        float v = X[i]; unsigned short h = f2bf(v);
        Xh[i] = h; Xl[i] = f2bf(v - bf2f(h)); return;
    }
    i -= B_*N_*DIN_;
    if (i < DG_*DIN_) {                                       // W1t [256][512] = Wg1^T split
        int o = i >> 9, k = i & 511;
        float v = Wg1[k*DG_ + o]; unsigned short h = f2bf(v);
        W1th[i] = h; W1tl[i] = f2bf(v - bf2f(h)); return;
    }
    i -= DG_*DIN_;
    if (i < DG_*DG_) {                                        // W2t [256][256] = Wg2^T split
        int o = i >> 8, k = i & 255;
        float v = Wg2[k*DG_ + o]; unsigned short h = f2bf(v);
        W2th[i] = h; W2tl[i] = f2bf(v - bf2f(h)); return;
    }
    i -= DG_*DG_;
    if (i < NH_*HID_) {                                       // Wb [1536][512] = concat W1^T bf16
        int n = i >> 9, k = i & 511;
        int head = n >> 9, h = n & 511;
        const float* W = head == 0 ? W1lr : (head == 1 ? W1cr : W1mr);
        Wb[i] = f2bf(W[k*HID_ + h]); return;
    }
    i -= NH_*HID_;
    if (i < 96*HID_) {                                        // W2b [96][512] = padded W2^T bf16
        int r = i >> 9, k = i & 511;
        int head = r >> 5, c = r & 31;
        int oc = head == 0 ? 6 : (head == 1 ? 5 : 14);
        const float* W = head == 0 ? W2lr : (head == 1 ? W2cr : W2mr);
        W2b[i] = (c < oc) ? f2bf(W[k*oc + c]) : (unsigned short)0; return;
    }
    i -= 96*HID_;
    if (i < NH_) {                                            // b1cat
        int head = i >> 9;
        const float* bb = head == 0 ? b1lr : (head == 1 ? b1cr : b1mr);
        b1cat[i] = bb[i & 511]; return;
    }
    i -= NH_;
    if (i < 96) {                                             // b2pad
        int head = i >> 5, c = i & 31;
        int oc = head == 0 ? 6 : (head == 1 ? 5 : 14);
        const float* bb = head == 0 ? b2lr : (head == 1 ? b2cr : b2mr);
        b2pad[i] = (c < oc) ? bb[c] : 0.0f;
    }
}

// -------- K4/K6: C[b][m<256][n<128] = sum_3terms A[m][K]*B[b][n][K], split store
// A = weight^T (shared), B^T = activation row-major (per batch). 3-term split-bf16.
__global__ __launch_bounds__(256) void k_gemm_w(
    const unsigned short* __restrict__ Ah, const unsigned short* __restrict__ Al,
    const unsigned short* __restrict__ Bh, const unsigned short* __restrict__ Bl,
    unsigned short* __restrict__ Oh, unsigned short* __restrict__ Ol, int K)
{
    int bid = blockIdx.x;
    int b = bid >> 2, m0 = (bid & 3) * 64;
    int t = threadIdx.x, lane = t & 63, w = t >> 6;
    int lm = lane & 15, quad = lane >> 4, q8 = quad * 8;
    const unsigned short* Bhb = Bh + (size_t)b * N_ * K;
    const unsigned short* Blb = Bl + (size_t)b * N_ * K;
    f32x4 acc[4][2];
    #pragma unroll
    for (int mi = 0; mi < 4; ++mi)
        #pragma unroll
        for (int ni = 0; ni < 2; ++ni) acc[mi][ni] = (f32x4){0.f, 0.f, 0.f, 0.f};
    for (int term = 0; term < 3; ++term) {   // (Ah,Bh) (Ah,Bl) (Al,Bh)
        const unsigned short* A  = (term == 2) ? Al  : Ah;
        const unsigned short* Bt = (term == 1) ? Blb : Bhb;
        for (int k0 = 0; k0 < K; k0 += 32) {
            bf16x8 av[4], bv[2];
            #pragma unroll
            for (int mi = 0; mi < 4; ++mi)
                av[mi] = *(const bf16x8*)(A + (size_t)(m0 + mi*16 + lm)*K + k0 + q8);
            #pragma unroll
            for (int ni = 0; ni < 2; ++ni)
                bv[ni] = *(const bf16x8*)(Bt + (size_t)(w*32 + ni*16 + lm)*K + k0 + q8);
            #pragma unroll
            for (int mi = 0; mi < 4; ++mi)
                #pragma unroll
                for (int ni = 0; ni < 2; ++ni)
                    acc[mi][ni] = mfma16(av[mi], bv[ni], acc[mi][ni]);
        }
    }
    #pragma unroll
    for (int mi = 0; mi < 4; ++mi)
        #pragma unroll
        for (int ni = 0; ni < 2; ++ni)
            #pragma unroll
            for (int r = 0; r < 4; ++r) {
                int m = m0 + mi*16 + quad*4 + r;
                int n = w*32 + ni*16 + lm;
                size_t o = ((size_t)b*256 + m)*128 + n;
                float v = acc[mi][ni][r];
                unsigned short h = f2bf(v);
                Oh[o] = h; Ol[o] = f2bf(v - bf2f(h));
            }
}

// -------- K5/K7: C[b][m<256][n<128] = relu( sum_2terms A[b][m][128]*Adj[b][n][128] )
// stored transposed [b][n][m]; mode 0: bf16 split pair, mode 1: fp32
__global__ __launch_bounds__(256) void k_gemm_a(
    const unsigned short* __restrict__ Ah, const unsigned short* __restrict__ Al,
    const unsigned short* __restrict__ Adj,
    unsigned short* __restrict__ Obh, unsigned short* __restrict__ Obl,
    float* __restrict__ Of, int mode)
{
    const int K = 128;
    int bid = blockIdx.x;
    int b = bid >> 2, m0 = (bid & 3) * 64;
    int t = threadIdx.x, lane = t & 63, w = t >> 6;
    int lm = lane & 15, quad = lane >> 4, q8 = quad * 8;
    const unsigned short* Ahb = Ah + (size_t)b * 256 * K;
    const unsigned short* Alb = Al + (size_t)b * 256 * K;
    const unsigned short* Bb  = Adj + (size_t)b * N_ * K;
    f32x4 acc[4][2];
    #pragma unroll
    for (int mi = 0; mi < 4; ++mi)
        #pragma unroll
        for (int ni = 0; ni < 2; ++ni) acc[mi][ni] = (f32x4){0.f, 0.f, 0.f, 0.f};
    for (int term = 0; term < 2; ++term) {
        const unsigned short* A = (term == 0) ? Ahb : Alb;
        for (int k0 = 0; k0 < K; k0 += 32) {
            bf16x8 av[4], bv[2];
            #pragma unroll
            for (int mi = 0; mi < 4; ++mi)
                av[mi] = *(const bf16x8*)(A + (size_t)(m0 + mi*16 + lm)*K + k0 + q8);
            #pragma unroll
            for (int ni = 0; ni < 2; ++ni)
                bv[ni] = *(const bf16x8*)(Bb + (size_t)(w*32 + ni*16 + lm)*K + k0 + q8);
            #pragma unroll
            for (int mi = 0; mi < 4; ++mi)
                #pragma unroll
                for (int ni = 0; ni < 2; ++ni)
                    acc[mi][ni] = mfma16(av[mi], bv[ni], acc[mi][ni]);
        }
    }
    #pragma unroll
    for (int mi = 0; mi < 4; ++mi)
        #pragma unroll
        for (int ni = 0; ni < 2; ++ni)
            #pragma unroll
            for (int r = 0; r < 4; ++r) {
                int m = m0 + mi*16 + quad*4 + r;
                int n = w*32 + ni*16 + lm;
                size_t o = ((size_t)b*128 + n)*256 + m;   // transposed store
                float v = fmaxf(acc[mi][ni][r], 0.f);
                if (mode == 0) {
                    unsigned short h = f2bf(v);
                    Obh[o] = h; Obl[o] = f2bf(v - bf2f(h));
                } else {
                    Of[o] = v;
                }
            }
}

// ---------------- K8: build ci = [emb(i0)+emb(i1) || IF(i0,i1)] as bf16 -----
__global__ __launch_bounds__(256) void k_gather(
    const float* __restrict__ emb, const float* __restrict__ iff,
    const int* __restrict__ pairs, unsigned short* __restrict__ CIb)
{
    int idx = blockIdx.x * 256 + threadIdx.x;    // 131072*128 float4 units
    int row = idx >> 7, q = idx & 127;
    int b = row >> 11;
    int i0 = pairs[row*2], i1 = pairs[row*2 + 1];
    f32x4 v;
    if (q < 64) {
        const f32x4* e0 = (const f32x4*)(emb + (size_t)(b*N_ + i0)*DG_);
        const f32x4* e1 = (const f32x4*)(emb + (size_t)(b*N_ + i1)*DG_);
        v = e0[q] + e1[q];
    } else {
        const f32x4* ef = (const f32x4*)(iff + ((size_t)(b*N_ + i0)*N_ + i1)*EF_);
        v = ef[q - 64];
    }
    us4 h;
    #pragma unroll
    for (int j = 0; j < 4; ++j) h[j] = f2bf(v[j]);
    *(us4*)(CIb + (size_t)row*512 + q*4) = h;
}

// ---------------- K9: fused 3-head MLP -------------------------------------
// block: 64 rows; 4 waves each compute a 64x64 hidden sub-tile per 256-col chunk.
// hidden -> LDS (C-layout -> A-layout) -> MFMA vs padded W2^T into persistent out accs.
__global__ __launch_bounds__(256) void k_mlp(
    const unsigned short* __restrict__ CIb, const unsigned short* __restrict__ Wb,
    const unsigned short* __restrict__ W2b, const float* __restrict__ b1cat,
    const float* __restrict__ b2pad, float* __restrict__ out)
{
    __shared__ __align__(16) unsigned short hid[64*264];   // 33792 B, pad 264 breaks bank stride
    int t = threadIdx.x, lane = t & 63, w = t >> 6;
    int lm = lane & 15, quad = lane >> 4, q8 = quad * 8;
    int row0 = blockIdx.x * 64;
    f32x4 accO[6];
    #pragma unroll
    for (int i = 0; i < 6; ++i) accO[i] = (f32x4){0.f, 0.f, 0.f, 0.f};

    for (int nt = 0; nt < 6; ++nt) {          // 6 chunks of 256 hidden cols; head = nt/2
        int head = nt >> 1;
        f32x4 acc[4][4];
        #pragma unroll
        for (int mi = 0; mi < 4; ++mi)
            #pragma unroll
            for (int ni = 0; ni < 4; ++ni) acc[mi][ni] = (f32x4){0.f, 0.f, 0.f, 0.f};
        const unsigned short* Wn = Wb + (size_t)(nt*256 + w*64)*512;
        for (int kt = 0; kt < 16; ++kt) {
            int k0 = kt*32 + q8;
            bf16x8 av[4], bv[4];
            #pragma unroll
            for (int mi = 0; mi < 4; ++mi)
                av[mi] = *(const bf16x8*)(CIb + (size_t)(row0 + mi*16 + lm)*512 + k0);
            #pragma unroll
            for (int ni = 0; ni < 4; ++ni)
                bv[ni] = *(const bf16x8*)(Wn + (size_t)(ni*16 + lm)*512 + k0);
            #pragma unroll
            for (int mi = 0; mi < 4; ++mi)
                #pragma unroll
                for (int ni = 0; ni < 4; ++ni)
                    acc[mi][ni] = mfma16(av[mi], bv[ni], acc[mi][ni]);
        }
        __syncthreads();   // previous chunk's mini-GEMM finished reading hid
        #pragma unroll
        for (int ni = 0; ni < 4; ++ni) {
            float bias = b1cat[nt*256 + w*64 + ni*16 + lm];
            #pragma unroll
            for (int mi = 0; mi < 4; ++mi)
                #pragma unroll
                for (int r = 0; r < 4; ++r) {
                    float v = fmaxf(acc[mi][ni][r] + bias, 0.f);
                    hid[(mi*16 + quad*4 + r)*264 + w*64 + ni*16 + lm] = f2bf(v);
                }
        }
        __syncthreads();
        int hb = (nt & 1) * 256;               // position within this head's 512 hiddens
        #pragma unroll
        for (int ki = 0; ki < 8; ++ki) {
            bf16x8 av = *(const bf16x8*)(hid + (size_t)(w*16 + lm)*264 + ki*32 + q8);
            #pragma unroll
            for (int ct = 0; ct < 2; ++ct) {
                bf16x8 bv = *(const bf16x8*)(W2b + (size_t)(head*32 + ct*16 + lm)*512 + hb + ki*32 + q8);
                accO[head*2 + ct] = mfma16(av, bv, accO[head*2 + ct]);
            }
        }
    }
    // epilogue: + b2, store to [row][25] with head col offsets {0,6,11}
    const int baseC[3] = {0, 6, 11};
    const int outc[3]  = {6, 5, 14};
    #pragma unroll
    for (int ht = 0; ht < 3; ++ht)
        #pragma unroll
        for (int ct = 0; ct < 2; ++ct) {
            int c = ct*16 + lm;
            if (c < outc[ht]) {
                float b2v = b2pad[ht*32 + c];
                #pragma unroll
                for (int r = 0; r < 4; ++r) {
                    int row = row0 + w*16 + quad*4 + r;
                    out[(size_t)row*25 + baseC[ht] + c] = accO[ht*2 + ct][r] + b2v;
                }
            }
        }
}

extern "C" void kernel_launch(void* const* d_in, const int* in_sizes, int n_in,
                              void* d_out, int out_size, void* d_ws, size_t ws_size,
                              hipStream_t stream)
{
    const float* X    = (const float*)d_in[0];
    const int*   ei   = (const int*)d_in[1];
    const int*   prs  = (const int*)d_in[2];
    const float* iff  = (const float*)d_in[3];
    const float* Wg1  = (const float*)d_in[4];
    const float* Wg2  = (const float*)d_in[5];
    const float* W1lr = (const float*)d_in[6];
    const float* b1lr = (const float*)d_in[7];
    const float* W2lr = (const float*)d_in[8];
    const float* b2lr = (const float*)d_in[9];
    const float* W1cr = (const float*)d_in[10];
    const float* b1cr = (const float*)d_in[11];
    const float* W2cr = (const float*)d_in[12];
    const float* b2cr = (const float*)d_in[13];
    const float* W1mr = (const float*)d_in[14];
    const float* b1mr = (const float*)d_in[15];
    const float* W2mr = (const float*)d_in[16];
    const float* b2mr = (const float*)d_in[17];
    float* out = (float*)d_out;

    char* p = (char*)d_ws;
    auto alloc = [&](size_t bytes) { char* r = p; p += (bytes + 255) & ~(size_t)255; return r; };
    float*          adjf = (float*)alloc(4ull*B_*N_*N_);
    unsigned short* adjb = (unsigned short*)alloc(2ull*B_*N_*N_);
    unsigned short* Xh   = (unsigned short*)alloc(2ull*B_*N_*DIN_);
    unsigned short* Xl   = (unsigned short*)alloc(2ull*B_*N_*DIN_);
    unsigned short* W1th = (unsigned short*)alloc(2ull*DG_*DIN_);
    unsigned short* W1tl = (unsigned short*)alloc(2ull*DG_*DIN_);
    unsigned short* W2th = (unsigned short*)alloc(2ull*DG_*DG_);
    unsigned short* W2tl = (unsigned short*)alloc(2ull*DG_*DG_);
    unsigned short* Y1h  = (unsigned short*)alloc(2ull*B_*256*128);
    unsigned short* Y1l  = (unsigned short*)alloc(2ull*B_*256*128);
    unsigned short* Hh   = (unsigned short*)alloc(2ull*B_*128*256);
    unsigned short* Hl   = (unsigned short*)alloc(2ull*B_*128*256);
    unsigned short* Y2h  = (unsigned short*)alloc(2ull*B_*256*128);
    unsigned short* Y2l  = (unsigned short*)alloc(2ull*B_*256*128);
    float*          emb  = (float*)alloc(4ull*B_*128*256);
    unsigned short* Wb   = (unsigned short*)alloc(2ull*NH_*HID_);
    unsigned short* W2b  = (unsigned short*)alloc(2ull*96*HID_);
    float*          b1c  = (float*)alloc(4ull*NH_);
    float*          b2p  = (float*)alloc(4ull*96);
    unsigned short* CIb  = (unsigned short*)alloc(2ull*MROWS_*512);

    k_init_adj<<<4096, 256, 0, stream>>>(adjf);
    k_scatter<<<1024, 256, 0, stream>>>(ei, adjf);
    const int TOT = B_*N_*N_ + B_*N_*DIN_ + DG_*DIN_ + DG_*DG_ + NH_*HID_ + 96*HID_ + NH_ + 96;
    k_prep<<<(TOT + 255)/256, 256, 0, stream>>>(
        adjf, X, Wg1, Wg2, W1lr, W1cr, W1mr, W2lr, W2cr, W2mr,
        b1lr, b1cr, b1mr, b2lr, b2cr, b2mr,
        adjb, Xh, Xl, W1th, W1tl, W2th, W2tl, Wb, W2b, b1c, b2p);
    // GCN layer 1: Y1t = W1t @ X^T  (split),  H = relu(Y1t @ Adj^T) stored [node][dg]
    k_gemm_w<<<256, 256, 0, stream>>>(W1th, W1tl, Xh, Xl, Y1h, Y1l, DIN_);
    k_gemm_a<<<256, 256, 0, stream>>>(Y1h, Y1l, adjb, Hh, Hl, (float*)nullptr, 0);
    // GCN layer 2: Y2t = W2t @ H^T (split), EMB = relu(Y2t @ Adj^T) fp32 [node][dg]
    k_gemm_w<<<256, 256, 0, stream>>>(W2th, W2tl, Hh, Hl, Y2h, Y2l, DG_);
    k_gemm_a<<<256, 256, 0, stream>>>(Y2h, Y2l, adjb, (unsigned short*)nullptr,
                                      (unsigned short*)nullptr, emb, 1);
    // pair features + fused MLP
    k_gather<<<65536, 256, 0, stream>>>(emb, iff, prs, CIb);
    k_mlp<<<2048, 256, 0, stream>>>(CIb, Wb, W2b, b1c, b2p, out);
}